// Round 1
// baseline (878.820 us; speedup 1.0000x reference)
//
#include <hip/hip_runtime.h>
#include <hip/hip_bf16.h>
#include <type_traits>
#include <math.h>

// ---------------------------------------------------------------------------
// Attention: out = softmax_causal((x Wq^T + bq)(x Wk^T + bk)^T / sqrt(D)) (x Wv^T + bv) Wp^T + bp
// B=4, S=2048, D=2048, fp32 in/out, bf16 MFMA compute.
//
// Workspace layout (needs 256 MB):
//   [0,32)MB   xb   bf16 x            [8192,2048]
//   [32,64)MB  wq/wk/wv/wp bf16       4 x [2048,2048] (8 MB each)
//   [64,96)MB  qb   bf16 Q            (later reused as attn P)
//   [96,128)MB kb   bf16 K            (later reused as ctx)
//   [128,160)MB vb  bf16 V
//   [160,192)MB vtb bf16 V^T per batch [D,S]
//   [192,256)MB sc  fp32 scores       [B,S,S]
// ---------------------------------------------------------------------------

typedef __bf16 bf16x8_t __attribute__((ext_vector_type(8)));
typedef float f32x4_t __attribute__((ext_vector_type(4)));
typedef unsigned short u16x8_t __attribute__((ext_vector_type(8)));

#define BM 128
#define BN 128
#define BK 32
#define PAD 8   // +8 bf16 (16B) keeps rows 16B-aligned, breaks 8-way bank conflict

__device__ inline unsigned short f2bf(float f) {
  // round-to-nearest-even bf16 (inputs are bounded; no NaN handling needed)
  unsigned int u = __builtin_bit_cast(unsigned int, f);
  unsigned int r = u + 0x7fffu + ((u >> 16) & 1u);
  return (unsigned short)(r >> 16);
}

// ---------------- cast fp32 -> bf16 (vectorized, n multiple of 4) ----------
__global__ __launch_bounds__(256) void cast_f32_bf16(
    const float* __restrict__ in, unsigned short* __restrict__ out, long n4) {
  long i = blockIdx.x * 256L + threadIdx.x;
  if (i >= n4) return;
  float4 f = ((const float4*)in)[i];
  ushort4 u;
  u.x = f2bf(f.x); u.y = f2bf(f.y); u.z = f2bf(f.z); u.w = f2bf(f.w);
  ((ushort4*)out)[i] = u;
}

// ---------------- bf16 2D transpose per batch ------------------------------
// out[b][c][r] = in[b][r][c];  grid (cols/32, rows/32, B), block (32,8)
__global__ __launch_bounds__(256) void transpose_bf16(
    const unsigned short* __restrict__ in, unsigned short* __restrict__ out,
    int rows, int cols) {
  __shared__ unsigned short tile[32][33];
  size_t off = (size_t)blockIdx.z * rows * cols;
  in += off; out += off;
  int c0 = blockIdx.x * 32, r0 = blockIdx.y * 32;
  int tx = threadIdx.x, ty = threadIdx.y;
#pragma unroll
  for (int i = 0; i < 32; i += 8)
    tile[ty + i][tx] = in[(size_t)(r0 + ty + i) * cols + c0 + tx];
  __syncthreads();
#pragma unroll
  for (int i = 0; i < 32; i += 8)
    out[(size_t)(c0 + ty + i) * rows + r0 + tx] = tile[tx][ty + i];
}

// ---------------- NT GEMM: C[m,n] = alpha * sum_k A[m,k]*B[n,k] + bias[n] --
// A:[M,K] bf16 row-major (lda=K), B:[N,K] bf16 row-major (ldb=K), C:[M,N]
// MODE 0: plain.  MODE 1: causal skip (drop blocks fully above diagonal).
// MODE 2: causal K-limit (K_eff = min(K, (block_row+1)*BM)) for attn*V.
// blockIdx.z batches with element strides sA/sB/sC.
template <int MODE, typename OutT>
__global__ __launch_bounds__(256) void gemm_nt(
    const unsigned short* __restrict__ A, const unsigned short* __restrict__ B,
    OutT* __restrict__ C, const float* __restrict__ bias, float alpha,
    int M, int N, int K, size_t sA, size_t sB, size_t sC) {
  const int bm = blockIdx.y * BM;
  const int bn = blockIdx.x * BN;
  if (MODE == 1 && bn >= bm + BM) return;  // fully-masked block
  int Keff = K;
  if (MODE == 2) { int kl = bm + BM; Keff = kl < K ? kl : K; }

  A += (size_t)blockIdx.z * sA;
  B += (size_t)blockIdx.z * sB;
  C += (size_t)blockIdx.z * sC;

  const int tid = threadIdx.x;
  const int lane = tid & 63;
  const int wave = tid >> 6;
  const int wm = (wave >> 1) * 64;  // 2x2 wave grid, 64x64 per wave
  const int wn = (wave & 1) * 64;

  __shared__ unsigned short As[BM][BK + PAD];
  __shared__ unsigned short Bs[BN][BK + PAD];

  // global->LDS mapping: 512 chunks of 8 bf16; thread t handles chunks t, t+256
  const int ar0 = tid >> 2, ak0 = (tid & 3) * 8;
  const int ar1 = (tid + 256) >> 2, ak1 = ((tid + 256) & 3) * 8;
  const unsigned short* Ab = A + (size_t)bm * K;
  const unsigned short* Bb = B + (size_t)bn * K;

  f32x4_t acc[4][4] = {};

  const int fr = lane & 15;          // A/B fragment row (m or n within 16)
  const int fk = (lane >> 4) * 8;    // fragment k offset

  for (int k0 = 0; k0 < Keff; k0 += BK) {
    u16x8_t a0 = *(const u16x8_t*)(Ab + (size_t)ar0 * K + k0 + ak0);
    u16x8_t a1 = *(const u16x8_t*)(Ab + (size_t)ar1 * K + k0 + ak1);
    u16x8_t b0 = *(const u16x8_t*)(Bb + (size_t)ar0 * K + k0 + ak0);
    u16x8_t b1 = *(const u16x8_t*)(Bb + (size_t)ar1 * K + k0 + ak1);
    __syncthreads();  // previous iter's LDS reads done
    *(u16x8_t*)&As[ar0][ak0] = a0;
    *(u16x8_t*)&As[ar1][ak1] = a1;
    *(u16x8_t*)&Bs[ar0][ak0] = b0;
    *(u16x8_t*)&Bs[ar1][ak1] = b1;
    __syncthreads();

    bf16x8_t af[4], bfv[4];
#pragma unroll
    for (int mi = 0; mi < 4; mi++)
      af[mi] = __builtin_bit_cast(bf16x8_t,
               *(const u16x8_t*)&As[wm + mi * 16 + fr][fk]);
#pragma unroll
    for (int ni = 0; ni < 4; ni++)
      bfv[ni] = __builtin_bit_cast(bf16x8_t,
                *(const u16x8_t*)&Bs[wn + ni * 16 + fr][fk]);
#pragma unroll
    for (int mi = 0; mi < 4; mi++)
#pragma unroll
      for (int ni = 0; ni < 4; ni++)
        acc[mi][ni] = __builtin_amdgcn_mfma_f32_16x16x32_bf16(
            af[mi], bfv[ni], acc[mi][ni], 0, 0, 0);
  }

  // epilogue: C/D layout col=lane&15, row=(lane>>4)*4+reg
  const int cr = (lane >> 4) * 4;
  const int cc = lane & 15;
#pragma unroll
  for (int ni = 0; ni < 4; ni++) {
    const int col = bn + wn + ni * 16 + cc;
    const float bs = bias ? bias[col] : 0.f;
#pragma unroll
    for (int mi = 0; mi < 4; mi++) {
      const int row = bm + wm + mi * 16 + cr;
#pragma unroll
      for (int r = 0; r < 4; r++) {
        float v = acc[mi][ni][r] * alpha + bs;
        if constexpr (std::is_same_v<OutT, float>)
          C[(size_t)(row + r) * N + col] = v;
        else
          C[(size_t)(row + r) * N + col] = f2bf(v);
      }
    }
  }
}

// ---------------- causal softmax: fp32 scores row -> bf16 attn row ----------
// one block per row; row q of batch b has valid cols [0, q]
__global__ __launch_bounds__(256) void softmax_causal(
    const float* __restrict__ Sc, unsigned short* __restrict__ P, int n) {
  const int row = blockIdx.x;
  const int q = row & (n - 1);  // n is a power of two
  const float* srow = Sc + (size_t)row * n;
  unsigned short* prow = P + (size_t)row * n;
  const int tid = threadIdx.x, lane = tid & 63, wid = tid >> 6;
  __shared__ float red[4];

  float m = -3.0e38f;
  for (int j = tid; j <= q; j += 256) m = fmaxf(m, srow[j]);
#pragma unroll
  for (int o = 32; o; o >>= 1) m = fmaxf(m, __shfl_down(m, o, 64));
  if (lane == 0) red[wid] = m;
  __syncthreads();
  m = fmaxf(fmaxf(red[0], red[1]), fmaxf(red[2], red[3]));
  __syncthreads();

  float s = 0.f;
  for (int j = tid; j <= q; j += 256) s += __expf(srow[j] - m);
#pragma unroll
  for (int o = 32; o; o >>= 1) s += __shfl_down(s, o, 64);
  if (lane == 0) red[wid] = s;
  __syncthreads();
  s = red[0] + red[1] + red[2] + red[3];
  const float inv = 1.f / s;

  for (int j = tid; j < n; j += 256) {
    float v = (j <= q) ? __expf(srow[j] - m) * inv : 0.f;  // zero masked region
    prow[j] = f2bf(v);
  }
}

// ---------------------------------------------------------------------------
extern "C" void kernel_launch(void* const* d_in, const int* in_sizes, int n_in,
                              void* d_out, int out_size, void* d_ws, size_t ws_size,
                              hipStream_t stream) {
  const int B = 4, S = 2048, D = 2048;
  const int M = B * S;  // 8192

  const float* x  = (const float*)d_in[0];
  // d_in[1] = mask: guaranteed causal tril, hardcoded in kernels
  const float* Wq = (const float*)d_in[2];
  const float* bq = (const float*)d_in[3];
  const float* Wk = (const float*)d_in[4];
  const float* bk = (const float*)d_in[5];
  const float* Wv = (const float*)d_in[6];
  const float* bv = (const float*)d_in[7];
  const float* Wp = (const float*)d_in[8];
  const float* bp = (const float*)d_in[9];
  float* out = (float*)d_out;

  char* ws = (char*)d_ws;
  const size_t MB = 1ull << 20;
  unsigned short* xb  = (unsigned short*)(ws + 0);
  unsigned short* wqb = (unsigned short*)(ws + 32 * MB);
  unsigned short* wkb = (unsigned short*)(ws + 40 * MB);
  unsigned short* wvb = (unsigned short*)(ws + 48 * MB);
  unsigned short* wpb = (unsigned short*)(ws + 56 * MB);
  unsigned short* qb  = (unsigned short*)(ws + 64 * MB);
  unsigned short* kb  = (unsigned short*)(ws + 96 * MB);
  unsigned short* vb  = (unsigned short*)(ws + 128 * MB);
  unsigned short* vtb = (unsigned short*)(ws + 160 * MB);
  float*          sc  = (float*)(ws + 192 * MB);  // 64 MB fp32 scores
  unsigned short* pb  = qb;  // attn reuses Q (dead after scores GEMM)
  unsigned short* cb  = kb;  // ctx reuses K (dead after scores GEMM)

  // 1) casts to bf16
  const long nx = (long)M * D;
  const long nw = (long)D * D;
  cast_f32_bf16<<<dim3((unsigned)((nx / 4 + 255) / 256)), 256, 0, stream>>>(x, xb, nx / 4);
  cast_f32_bf16<<<dim3((unsigned)((nw / 4 + 255) / 256)), 256, 0, stream>>>(Wq, wqb, nw / 4);
  cast_f32_bf16<<<dim3((unsigned)((nw / 4 + 255) / 256)), 256, 0, stream>>>(Wk, wkb, nw / 4);
  cast_f32_bf16<<<dim3((unsigned)((nw / 4 + 255) / 256)), 256, 0, stream>>>(Wv, wvb, nw / 4);
  cast_f32_bf16<<<dim3((unsigned)((nw / 4 + 255) / 256)), 256, 0, stream>>>(Wp, wpb, nw / 4);

  const dim3 blk(256);
  const dim3 gproj(D / BN, M / BM, 1);  // (16, 64)

  // 2) Q/K/V projections (bf16 out)
  gemm_nt<0, unsigned short><<<gproj, blk, 0, stream>>>(xb, wqb, qb, bq, 1.f, M, D, D, 0, 0, 0);
  gemm_nt<0, unsigned short><<<gproj, blk, 0, stream>>>(xb, wkb, kb, bk, 1.f, M, D, D, 0, 0, 0);
  gemm_nt<0, unsigned short><<<gproj, blk, 0, stream>>>(xb, wvb, vb, bv, 1.f, M, D, D, 0, 0, 0);

  // 3) V^T per batch: [S,D] -> [D,S]
  transpose_bf16<<<dim3(D / 32, S / 32, B), dim3(32, 8), 0, stream>>>(vb, vtb, S, D);

  // 4) scores = Q K^T * inv_std (fp32 out, causal block skip)
  const float inv_std = 1.f / sqrtf((float)D);
  gemm_nt<1, float><<<dim3(S / BN, S / BM, B), blk, 0, stream>>>(
      qb, kb, sc, nullptr, inv_std, S, S, D, (size_t)S * D, (size_t)S * D, (size_t)S * S);

  // 5) causal softmax -> bf16 attn
  softmax_causal<<<dim3(B * S), blk, 0, stream>>>(sc, pb, S);

  // 6) ctx = attn @ V  (via V^T, NT form; K-range capped at diagonal)
  gemm_nt<2, unsigned short><<<dim3(D / BN, S / BM, B), blk, 0, stream>>>(
      pb, vtb, cb, nullptr, 1.f, S, D, S, (size_t)S * S, (size_t)D * S, (size_t)S * D);

  // 7) out = ctx Wp^T + bp (fp32 out)
  gemm_nt<0, float><<<gproj, blk, 0, stream>>>(cb, wpb, out, bp, 1.f, M, D, D, 0, 0, 0);
}

// Round 2
// 860.443 us; speedup vs baseline: 1.0214x; 1.0214x over previous
//
#include <hip/hip_runtime.h>
#include <hip/hip_bf16.h>
#include <type_traits>
#include <math.h>

// ---------------------------------------------------------------------------
// Attention: out = softmax_causal((x Wq^T + bq)(x Wk^T + bk)^T / sqrt(D)) (x Wv^T + bv) Wp^T + bp
// B=4, S=2048, D=2048, fp32 in/out, bf16 MFMA compute.
//
// R1: gemm_nt staging switched to __builtin_amdgcn_global_load_lds width=16
// (m97 structure: unpadded [128][32] LDS tiles, 2-barrier K-loop).
//
// Workspace layout (needs 256 MB):
//   [0,32)MB   xb   bf16 x            [8192,2048]
//   [32,64)MB  wq/wk/wv/wp bf16       4 x [2048,2048] (8 MB each)
//   [64,96)MB  qb   bf16 Q            (later reused as attn P)
//   [96,128)MB kb   bf16 K            (later reused as ctx)
//   [128,160)MB vb  bf16 V
//   [160,192)MB vtb bf16 V^T per batch [D,S]
//   [192,256)MB sc  fp32 scores       [B,S,S]
// ---------------------------------------------------------------------------

typedef __bf16 bf16x8_t __attribute__((ext_vector_type(8)));
typedef float f32x4_t __attribute__((ext_vector_type(4)));
typedef unsigned short u16x8_t __attribute__((ext_vector_type(8)));

#define BM 128
#define BN 128
#define BK 32

__device__ inline unsigned short f2bf(float f) {
  // round-to-nearest-even bf16 (inputs are bounded; no NaN handling needed)
  unsigned int u = __builtin_bit_cast(unsigned int, f);
  unsigned int r = u + 0x7fffu + ((u >> 16) & 1u);
  return (unsigned short)(r >> 16);
}

// async global->LDS, 16B per lane; lds dest = wave-uniform base + lane*16
__device__ inline void gl2lds16(const unsigned short* g, unsigned short* l) {
  __builtin_amdgcn_global_load_lds(
      (const __attribute__((address_space(1))) unsigned int*)g,
      (__attribute__((address_space(3))) unsigned int*)l, 16, 0, 0);
}

// ---------------- cast fp32 -> bf16 (vectorized, n multiple of 4) ----------
__global__ __launch_bounds__(256) void cast_f32_bf16(
    const float* __restrict__ in, unsigned short* __restrict__ out, long n4) {
  long i = blockIdx.x * 256L + threadIdx.x;
  if (i >= n4) return;
  float4 f = ((const float4*)in)[i];
  ushort4 u;
  u.x = f2bf(f.x); u.y = f2bf(f.y); u.z = f2bf(f.z); u.w = f2bf(f.w);
  ((ushort4*)out)[i] = u;
}

// ---------------- bf16 2D transpose per batch ------------------------------
// out[b][c][r] = in[b][r][c];  grid (cols/32, rows/32, B), block (32,8)
__global__ __launch_bounds__(256) void transpose_bf16(
    const unsigned short* __restrict__ in, unsigned short* __restrict__ out,
    int rows, int cols) {
  __shared__ unsigned short tile[32][33];
  size_t off = (size_t)blockIdx.z * rows * cols;
  in += off; out += off;
  int c0 = blockIdx.x * 32, r0 = blockIdx.y * 32;
  int tx = threadIdx.x, ty = threadIdx.y;
#pragma unroll
  for (int i = 0; i < 32; i += 8)
    tile[ty + i][tx] = in[(size_t)(r0 + ty + i) * cols + c0 + tx];
  __syncthreads();
#pragma unroll
  for (int i = 0; i < 32; i += 8)
    out[(size_t)(c0 + ty + i) * rows + r0 + tx] = tile[tx][ty + i];
}

// ---------------- NT GEMM: C[m,n] = alpha * sum_k A[m,k]*B[n,k] + bias[n] --
// A:[M,K] bf16 row-major (lda=K), B:[N,K] bf16 row-major (ldb=K), C:[M,N]
// MODE 0: plain.  MODE 1: causal skip (drop blocks fully above diagonal).
// MODE 2: causal K-limit (K_eff = min(K, (block_row+1)*BM)) for attn*V.
// blockIdx.z batches with element strides sA/sB/sC.
template <int MODE, typename OutT>
__global__ __launch_bounds__(256) void gemm_nt(
    const unsigned short* __restrict__ A, const unsigned short* __restrict__ B,
    OutT* __restrict__ C, const float* __restrict__ bias, float alpha,
    int M, int N, int K, size_t sA, size_t sB, size_t sC) {
  const int bm = blockIdx.y * BM;
  const int bn = blockIdx.x * BN;
  if (MODE == 1 && bn >= bm + BM) return;  // fully-masked block
  int Keff = K;
  if (MODE == 2) { int kl = bm + BM; Keff = kl < K ? kl : K; }

  A += (size_t)blockIdx.z * sA;
  B += (size_t)blockIdx.z * sB;
  C += (size_t)blockIdx.z * sC;

  const int tid = threadIdx.x;
  const int lane = tid & 63;
  const int wave = tid >> 6;
  const int wm = (wave >> 1) * 64;  // 2x2 wave grid, 64x64 per wave
  const int wn = (wave & 1) * 64;

  // UNPADDED tiles — required by global_load_lds lane->LDS mapping.
  // A-tile [128][32] bf16 = 8 KB, B-tile same. 16 KB total.
  __shared__ unsigned short smem[2 * BM * BK];
  unsigned short* As = smem;
  unsigned short* Bs = smem + BM * BK;

  // staging map: tile = 8 chunks of 1 KB; wave w covers chunks {2w, 2w+1};
  // within a chunk lane l writes LDS bytes [l*16, l*16+16) which is
  // row = chunk*16 + l/4, kofs = (l&3)*8 of the [128][32] tile.
  const int chunk0 = wave * 2, chunk1 = wave * 2 + 1;
  const int sr0 = chunk0 * 16 + (lane >> 2);
  const int sr1 = chunk1 * 16 + (lane >> 2);
  const int skofs = (lane & 3) * 8;
  unsigned short* ldsA0 = As + chunk0 * 512;  // 512 elems = 1 KB
  unsigned short* ldsA1 = As + chunk1 * 512;
  unsigned short* ldsB0 = Bs + chunk0 * 512;
  unsigned short* ldsB1 = Bs + chunk1 * 512;

  const unsigned short* Ab = A + (size_t)bm * K;
  const unsigned short* Bb = B + (size_t)bn * K;

  f32x4_t acc[4][4] = {};

  const int fr = lane & 15;          // A/B fragment row (m or n within 16)
  const int fk = (lane >> 4) * 8;    // fragment k offset

  for (int k0 = 0; k0 < Keff; k0 += BK) {
    __syncthreads();  // previous iter's LDS reads complete before overwrite
    gl2lds16(Ab + (size_t)sr0 * K + k0 + skofs, ldsA0);
    gl2lds16(Ab + (size_t)sr1 * K + k0 + skofs, ldsA1);
    gl2lds16(Bb + (size_t)sr0 * K + k0 + skofs, ldsB0);
    gl2lds16(Bb + (size_t)sr1 * K + k0 + skofs, ldsB1);
    __syncthreads();  // drains vmcnt -> tile visible

    bf16x8_t af[4], bfv[4];
#pragma unroll
    for (int mi = 0; mi < 4; mi++)
      af[mi] = __builtin_bit_cast(bf16x8_t,
               *(const u16x8_t*)&As[(wm + mi * 16 + fr) * BK + fk]);
#pragma unroll
    for (int ni = 0; ni < 4; ni++)
      bfv[ni] = __builtin_bit_cast(bf16x8_t,
                *(const u16x8_t*)&Bs[(wn + ni * 16 + fr) * BK + fk]);
#pragma unroll
    for (int mi = 0; mi < 4; mi++)
#pragma unroll
      for (int ni = 0; ni < 4; ni++)
        acc[mi][ni] = __builtin_amdgcn_mfma_f32_16x16x32_bf16(
            af[mi], bfv[ni], acc[mi][ni], 0, 0, 0);
  }

  // epilogue: C/D layout col=lane&15, row=(lane>>4)*4+reg
  const int cr = (lane >> 4) * 4;
  const int cc = lane & 15;
#pragma unroll
  for (int ni = 0; ni < 4; ni++) {
    const int col = bn + wn + ni * 16 + cc;
    const float bs = bias ? bias[col] : 0.f;
#pragma unroll
    for (int mi = 0; mi < 4; mi++) {
      const int row = bm + wm + mi * 16 + cr;
#pragma unroll
      for (int r = 0; r < 4; r++) {
        float v = acc[mi][ni][r] * alpha + bs;
        if constexpr (std::is_same_v<OutT, float>)
          C[(size_t)(row + r) * N + col] = v;
        else
          C[(size_t)(row + r) * N + col] = f2bf(v);
      }
    }
  }
}

// ---------------- causal softmax: fp32 scores row -> bf16 attn row ----------
// one block per row; row q of batch b has valid cols [0, q]
__global__ __launch_bounds__(256) void softmax_causal(
    const float* __restrict__ Sc, unsigned short* __restrict__ P, int n) {
  const int row = blockIdx.x;
  const int q = row & (n - 1);  // n is a power of two
  const float* srow = Sc + (size_t)row * n;
  unsigned short* prow = P + (size_t)row * n;
  const int tid = threadIdx.x, lane = tid & 63, wid = tid >> 6;
  __shared__ float red[4];

  float m = -3.0e38f;
  for (int j = tid; j <= q; j += 256) m = fmaxf(m, srow[j]);
#pragma unroll
  for (int o = 32; o; o >>= 1) m = fmaxf(m, __shfl_down(m, o, 64));
  if (lane == 0) red[wid] = m;
  __syncthreads();
  m = fmaxf(fmaxf(red[0], red[1]), fmaxf(red[2], red[3]));
  __syncthreads();

  float s = 0.f;
  for (int j = tid; j <= q; j += 256) s += __expf(srow[j] - m);
#pragma unroll
  for (int o = 32; o; o >>= 1) s += __shfl_down(s, o, 64);
  if (lane == 0) red[wid] = s;
  __syncthreads();
  s = red[0] + red[1] + red[2] + red[3];
  const float inv = 1.f / s;

  for (int j = tid; j < n; j += 256) {
    float v = (j <= q) ? __expf(srow[j] - m) * inv : 0.f;  // zero masked region
    prow[j] = f2bf(v);
  }
}

// ---------------------------------------------------------------------------
extern "C" void kernel_launch(void* const* d_in, const int* in_sizes, int n_in,
                              void* d_out, int out_size, void* d_ws, size_t ws_size,
                              hipStream_t stream) {
  const int B = 4, S = 2048, D = 2048;
  const int M = B * S;  // 8192

  const float* x  = (const float*)d_in[0];
  // d_in[1] = mask: guaranteed causal tril, hardcoded in kernels
  const float* Wq = (const float*)d_in[2];
  const float* bq = (const float*)d_in[3];
  const float* Wk = (const float*)d_in[4];
  const float* bk = (const float*)d_in[5];
  const float* Wv = (const float*)d_in[6];
  const float* bv = (const float*)d_in[7];
  const float* Wp = (const float*)d_in[8];
  const float* bp = (const float*)d_in[9];
  float* out = (float*)d_out;

  char* ws = (char*)d_ws;
  const size_t MB = 1ull << 20;
  unsigned short* xb  = (unsigned short*)(ws + 0);
  unsigned short* wqb = (unsigned short*)(ws + 32 * MB);
  unsigned short* wkb = (unsigned short*)(ws + 40 * MB);
  unsigned short* wvb = (unsigned short*)(ws + 48 * MB);
  unsigned short* wpb = (unsigned short*)(ws + 56 * MB);
  unsigned short* qb  = (unsigned short*)(ws + 64 * MB);
  unsigned short* kb  = (unsigned short*)(ws + 96 * MB);
  unsigned short* vb  = (unsigned short*)(ws + 128 * MB);
  unsigned short* vtb = (unsigned short*)(ws + 160 * MB);
  float*          sc  = (float*)(ws + 192 * MB);  // 64 MB fp32 scores
  unsigned short* pb  = qb;  // attn reuses Q (dead after scores GEMM)
  unsigned short* cb  = kb;  // ctx reuses K (dead after scores GEMM)

  // 1) casts to bf16
  const long nx = (long)M * D;
  const long nw = (long)D * D;
  cast_f32_bf16<<<dim3((unsigned)((nx / 4 + 255) / 256)), 256, 0, stream>>>(x, xb, nx / 4);
  cast_f32_bf16<<<dim3((unsigned)((nw / 4 + 255) / 256)), 256, 0, stream>>>(Wq, wqb, nw / 4);
  cast_f32_bf16<<<dim3((unsigned)((nw / 4 + 255) / 256)), 256, 0, stream>>>(Wk, wkb, nw / 4);
  cast_f32_bf16<<<dim3((unsigned)((nw / 4 + 255) / 256)), 256, 0, stream>>>(Wv, wvb, nw / 4);
  cast_f32_bf16<<<dim3((unsigned)((nw / 4 + 255) / 256)), 256, 0, stream>>>(Wp, wpb, nw / 4);

  const dim3 blk(256);
  const dim3 gproj(D / BN, M / BM, 1);  // (16, 64)

  // 2) Q/K/V projections (bf16 out)
  gemm_nt<0, unsigned short><<<gproj, blk, 0, stream>>>(xb, wqb, qb, bq, 1.f, M, D, D, 0, 0, 0);
  gemm_nt<0, unsigned short><<<gproj, blk, 0, stream>>>(xb, wkb, kb, bk, 1.f, M, D, D, 0, 0, 0);
  gemm_nt<0, unsigned short><<<gproj, blk, 0, stream>>>(xb, wvb, vb, bv, 1.f, M, D, D, 0, 0, 0);

  // 3) V^T per batch: [S,D] -> [D,S]
  transpose_bf16<<<dim3(D / 32, S / 32, B), dim3(32, 8), 0, stream>>>(vb, vtb, S, D);

  // 4) scores = Q K^T * inv_std (fp32 out, causal block skip)
  const float inv_std = 1.f / sqrtf((float)D);
  gemm_nt<1, float><<<dim3(S / BN, S / BM, B), blk, 0, stream>>>(
      qb, kb, sc, nullptr, inv_std, S, S, D, (size_t)S * D, (size_t)S * D, (size_t)S * S);

  // 5) causal softmax -> bf16 attn
  softmax_causal<<<dim3(B * S), blk, 0, stream>>>(sc, pb, S);

  // 6) ctx = attn @ V  (via V^T, NT form; K-range capped at diagonal)
  gemm_nt<2, unsigned short><<<dim3(D / BN, S / BM, B), blk, 0, stream>>>(
      pb, vtb, cb, nullptr, 1.f, S, D, S, (size_t)S * S, (size_t)D * S, (size_t)S * D);

  // 7) out = ctx Wp^T + bp (fp32 out)
  gemm_nt<0, float><<<gproj, blk, 0, stream>>>(cb, wpb, out, bp, 1.f, M, D, D, 0, 0, 0);
}

// Round 3
// 766.821 us; speedup vs baseline: 1.1461x; 1.1221x over previous
//
#include <hip/hip_runtime.h>
#include <hip/hip_bf16.h>
#include <type_traits>
#include <math.h>

// ---------------------------------------------------------------------------
// Attention: out = softmax_causal((x Wq^T + bq)(x Wk^T + bk)^T / sqrt(D)) (x Wv^T + bv) Wp^T + bp
// B=4, S=2048, D=2048, fp32 in/out, bf16 MFMA compute.
//
// R2: QKV projections fused into one GEMM (N=6144, 3072 blocks) with a
// triple-destination epilogue (Q, K normal; V written transposed as ushort4 —
// deletes the standalone transpose kernel). Weight casts fused to one launch.
//
// Workspace layout (256 MB):
//   [0,32)MB    xb    bf16 x              [8192,2048]
//   [32,56)MB   wqkv  bf16 [Wq;Wk;Wv]     [6144,2048]
//   [56,64)MB   wpb   bf16 Wp             [2048,2048]
//   [64,96)MB   qb    bf16 Q              (later reused as attn P)
//   [96,128)MB  kb    bf16 K              (later reused as ctx)
//   [160,192)MB vtb   bf16 V^T per batch  [B][D][S]
//   [192,256)MB sc    fp32 scores         [B,S,S]
// ---------------------------------------------------------------------------

typedef __bf16 bf16x8_t __attribute__((ext_vector_type(8)));
typedef float f32x4_t __attribute__((ext_vector_type(4)));
typedef unsigned short u16x8_t __attribute__((ext_vector_type(8)));

#define BM 128
#define BN 128
#define BK 32

__device__ inline unsigned short f2bf(float f) {
  unsigned int u = __builtin_bit_cast(unsigned int, f);
  unsigned int r = u + 0x7fffu + ((u >> 16) & 1u);
  return (unsigned short)(r >> 16);
}

// async global->LDS, 16B per lane; lds dest = wave-uniform base + lane*16
__device__ inline void gl2lds16(const unsigned short* g, unsigned short* l) {
  __builtin_amdgcn_global_load_lds(
      (const __attribute__((address_space(1))) unsigned int*)g,
      (__attribute__((address_space(3))) unsigned int*)l, 16, 0, 0);
}

// ---------------- cast fp32 -> bf16 (x input) ------------------------------
__global__ __launch_bounds__(256) void cast_f32_bf16(
    const float* __restrict__ in, unsigned short* __restrict__ out, long n4) {
  long i = blockIdx.x * 256L + threadIdx.x;
  if (i >= n4) return;
  float4 f = ((const float4*)in)[i];
  ushort4 u;
  u.x = f2bf(f.x); u.y = f2bf(f.y); u.z = f2bf(f.z); u.w = f2bf(f.w);
  ((ushort4*)out)[i] = u;
}

// ---------------- fused 4-weight cast: blockIdx.y selects matrix -----------
__global__ __launch_bounds__(256) void cast_w4(
    const float* __restrict__ w0, const float* __restrict__ w1,
    const float* __restrict__ w2, const float* __restrict__ w3,
    unsigned short* __restrict__ o0, unsigned short* __restrict__ o1,
    unsigned short* __restrict__ o2, unsigned short* __restrict__ o3,
    long n4) {
  long i = blockIdx.x * 256L + threadIdx.x;
  if (i >= n4) return;
  const float* in; unsigned short* out;
  switch (blockIdx.y) {
    case 0: in = w0; out = o0; break;
    case 1: in = w1; out = o1; break;
    case 2: in = w2; out = o2; break;
    default: in = w3; out = o3; break;
  }
  float4 f = ((const float4*)in)[i];
  ushort4 u;
  u.x = f2bf(f.x); u.y = f2bf(f.y); u.z = f2bf(f.z); u.w = f2bf(f.w);
  ((ushort4*)out)[i] = u;
}

// ===================== shared GEMM K-loop (macro body) =====================
// Declares/uses: As,Bs, staging indices, acc[4][4]; A-tile from Ab (lda=K),
// B-tile from Bb (ldb=K), iterates k0 in [0,Keff).
#define GEMM_PROLOGUE()                                                        \
  const int tid = threadIdx.x;                                                 \
  const int lane = tid & 63;                                                   \
  const int wave = tid >> 6;                                                   \
  const int wm = (wave >> 1) * 64;                                             \
  const int wn = (wave & 1) * 64;                                              \
  __shared__ unsigned short smem[2 * BM * BK];                                 \
  unsigned short* As = smem;                                                   \
  unsigned short* Bs = smem + BM * BK;                                         \
  const int chunk0 = wave * 2, chunk1 = wave * 2 + 1;                          \
  const int sr0 = chunk0 * 16 + (lane >> 2);                                   \
  const int sr1 = chunk1 * 16 + (lane >> 2);                                   \
  const int skofs = (lane & 3) * 8;                                            \
  unsigned short* ldsA0 = As + chunk0 * 512;                                   \
  unsigned short* ldsA1 = As + chunk1 * 512;                                   \
  unsigned short* ldsB0 = Bs + chunk0 * 512;                                   \
  unsigned short* ldsB1 = Bs + chunk1 * 512;                                   \
  f32x4_t acc[4][4] = {};                                                      \
  const int fr = lane & 15;                                                    \
  const int fk = (lane >> 4) * 8;

#define GEMM_KLOOP(Ab, Bb, K, Keff)                                            \
  for (int k0 = 0; k0 < (Keff); k0 += BK) {                                    \
    __syncthreads();                                                           \
    gl2lds16((Ab) + (size_t)sr0 * (K) + k0 + skofs, ldsA0);                    \
    gl2lds16((Ab) + (size_t)sr1 * (K) + k0 + skofs, ldsA1);                    \
    gl2lds16((Bb) + (size_t)sr0 * (K) + k0 + skofs, ldsB0);                    \
    gl2lds16((Bb) + (size_t)sr1 * (K) + k0 + skofs, ldsB1);                    \
    __syncthreads();                                                           \
    bf16x8_t af[4], bfv[4];                                                    \
    _Pragma("unroll")                                                          \
    for (int mi = 0; mi < 4; mi++)                                             \
      af[mi] = __builtin_bit_cast(                                             \
          bf16x8_t, *(const u16x8_t*)&As[(wm + mi * 16 + fr) * BK + fk]);      \
    _Pragma("unroll")                                                          \
    for (int ni = 0; ni < 4; ni++)                                             \
      bfv[ni] = __builtin_bit_cast(                                            \
          bf16x8_t, *(const u16x8_t*)&Bs[(wn + ni * 16 + fr) * BK + fk]);      \
    _Pragma("unroll")                                                          \
    for (int mi = 0; mi < 4; mi++)                                             \
      _Pragma("unroll")                                                        \
      for (int ni = 0; ni < 4; ni++)                                           \
        acc[mi][ni] = __builtin_amdgcn_mfma_f32_16x16x32_bf16(                 \
            af[mi], bfv[ni], acc[mi][ni], 0, 0, 0);                            \
  }

// ---------------- generic NT GEMM (modes 0/1/2), as in R1 ------------------
template <int MODE, typename OutT>
__global__ __launch_bounds__(256) void gemm_nt(
    const unsigned short* __restrict__ A, const unsigned short* __restrict__ B,
    OutT* __restrict__ C, const float* __restrict__ bias, float alpha,
    int M, int N, int K, size_t sA, size_t sB, size_t sC) {
  const int bm = blockIdx.y * BM;
  const int bn = blockIdx.x * BN;
  if (MODE == 1 && bn >= bm + BM) return;
  int Keff = K;
  if (MODE == 2) { int kl = bm + BM; Keff = kl < K ? kl : K; }

  A += (size_t)blockIdx.z * sA;
  B += (size_t)blockIdx.z * sB;
  C += (size_t)blockIdx.z * sC;

  GEMM_PROLOGUE();
  const unsigned short* Ab = A + (size_t)bm * K;
  const unsigned short* Bb = B + (size_t)bn * K;
  GEMM_KLOOP(Ab, Bb, K, Keff);

  const int cr = (lane >> 4) * 4;
  const int cc = lane & 15;
#pragma unroll
  for (int ni = 0; ni < 4; ni++) {
    const int col = bn + wn + ni * 16 + cc;
    const float bs = bias ? bias[col] : 0.f;
#pragma unroll
    for (int mi = 0; mi < 4; mi++) {
      const int row = bm + wm + mi * 16 + cr;
#pragma unroll
      for (int r = 0; r < 4; r++) {
        float v = acc[mi][ni][r] * alpha + bs;
        if constexpr (std::is_same_v<OutT, float>)
          C[(size_t)(row + r) * N + col] = v;
        else
          C[(size_t)(row + r) * N + col] = f2bf(v);
      }
    }
  }
}

// ---------------- fused QKV GEMM: N = 3*D, triple-destination epilogue -----
// B matrix = [Wq;Wk;Wv] stacked rows [3D, D]. col<D -> Q, col<2D -> K,
// else V stored TRANSPOSED per batch: vtb[b][d][s] (contiguous ushort4 in s).
__global__ __launch_bounds__(256) void gemm_qkv(
    const unsigned short* __restrict__ A, const unsigned short* __restrict__ Bw,
    unsigned short* __restrict__ Q, unsigned short* __restrict__ Kd,
    unsigned short* __restrict__ Vt,
    const float* __restrict__ bq, const float* __restrict__ bk,
    const float* __restrict__ bv, int K, int D, int S) {
  const int bm = blockIdx.y * BM;
  const int bn = blockIdx.x * BN;

  GEMM_PROLOGUE();
  const unsigned short* Ab = A + (size_t)bm * K;
  const unsigned short* Bb = Bw + (size_t)bn * K;
  GEMM_KLOOP(Ab, Bb, K, K);

  const int cr = (lane >> 4) * 4;
  const int cc = lane & 15;
#pragma unroll
  for (int ni = 0; ni < 4; ni++) {
    const int col = bn + wn + ni * 16 + cc;       // [0, 3D)
    const int sel = col >> 11;                    // 0:Q 1:K 2:V (D=2048)
    const int idx = col & (D - 1);
    const float bs = (sel == 0 ? bq : sel == 1 ? bk : bv)[idx];
#pragma unroll
    for (int mi = 0; mi < 4; mi++) {
      const int row = bm + wm + mi * 16 + cr;
      if (sel < 2) {
        unsigned short* dst = sel == 0 ? Q : Kd;
#pragma unroll
        for (int r = 0; r < 4; r++)
          dst[(size_t)(row + r) * D + idx] = f2bf(acc[mi][ni][r] + bs);
      } else {
        const int b = row >> 11;                  // S=2048
        const int s = row & (S - 1);              // multiple of 4
        ushort4 pack;
        pack.x = f2bf(acc[mi][ni][0] + bs);
        pack.y = f2bf(acc[mi][ni][1] + bs);
        pack.z = f2bf(acc[mi][ni][2] + bs);
        pack.w = f2bf(acc[mi][ni][3] + bs);
        *(ushort4*)&Vt[(size_t)b * D * S + (size_t)idx * S + s] = pack;
      }
    }
  }
}

// ---------------- causal softmax: fp32 scores row -> bf16 attn row ----------
__global__ __launch_bounds__(256) void softmax_causal(
    const float* __restrict__ Sc, unsigned short* __restrict__ P, int n) {
  const int row = blockIdx.x;
  const int q = row & (n - 1);
  const float* srow = Sc + (size_t)row * n;
  unsigned short* prow = P + (size_t)row * n;
  const int tid = threadIdx.x, lane = tid & 63, wid = tid >> 6;
  __shared__ float red[4];

  float m = -3.0e38f;
  for (int j = tid; j <= q; j += 256) m = fmaxf(m, srow[j]);
#pragma unroll
  for (int o = 32; o; o >>= 1) m = fmaxf(m, __shfl_down(m, o, 64));
  if (lane == 0) red[wid] = m;
  __syncthreads();
  m = fmaxf(fmaxf(red[0], red[1]), fmaxf(red[2], red[3]));
  __syncthreads();

  float s = 0.f;
  for (int j = tid; j <= q; j += 256) s += __expf(srow[j] - m);
#pragma unroll
  for (int o = 32; o; o >>= 1) s += __shfl_down(s, o, 64);
  if (lane == 0) red[wid] = s;
  __syncthreads();
  s = red[0] + red[1] + red[2] + red[3];
  const float inv = 1.f / s;

  for (int j = tid; j < n; j += 256) {
    float v = (j <= q) ? __expf(srow[j] - m) * inv : 0.f;
    prow[j] = f2bf(v);
  }
}

// ---------------------------------------------------------------------------
extern "C" void kernel_launch(void* const* d_in, const int* in_sizes, int n_in,
                              void* d_out, int out_size, void* d_ws, size_t ws_size,
                              hipStream_t stream) {
  const int B = 4, S = 2048, D = 2048;
  const int M = B * S;  // 8192

  const float* x  = (const float*)d_in[0];
  // d_in[1] = mask: guaranteed causal tril, hardcoded in kernels
  const float* Wq = (const float*)d_in[2];
  const float* bq = (const float*)d_in[3];
  const float* Wk = (const float*)d_in[4];
  const float* bk = (const float*)d_in[5];
  const float* Wv = (const float*)d_in[6];
  const float* bv = (const float*)d_in[7];
  const float* Wp = (const float*)d_in[8];
  const float* bp = (const float*)d_in[9];
  float* out = (float*)d_out;

  char* ws = (char*)d_ws;
  const size_t MB = 1ull << 20;
  unsigned short* xb   = (unsigned short*)(ws + 0);
  unsigned short* wqkv = (unsigned short*)(ws + 32 * MB);  // [6144,2048]
  unsigned short* wpb  = (unsigned short*)(ws + 56 * MB);
  unsigned short* qb   = (unsigned short*)(ws + 64 * MB);
  unsigned short* kb   = (unsigned short*)(ws + 96 * MB);
  unsigned short* vtb  = (unsigned short*)(ws + 160 * MB);
  float*          sc   = (float*)(ws + 192 * MB);
  unsigned short* pb   = qb;  // attn reuses Q (dead after scores GEMM)
  unsigned short* cb   = kb;  // ctx reuses K (dead after scores GEMM)

  const long nx = (long)M * D;
  const long nw = (long)D * D;

  // 1) casts: x, then all 4 weights in one launch (into stacked layout)
  cast_f32_bf16<<<dim3((unsigned)((nx / 4 + 255) / 256)), 256, 0, stream>>>(x, xb, nx / 4);
  cast_w4<<<dim3((unsigned)((nw / 4 + 255) / 256), 4), 256, 0, stream>>>(
      Wq, Wk, Wv, Wp,
      wqkv, wqkv + (size_t)D * D, wqkv + 2 * (size_t)D * D, wpb, nw / 4);

  const dim3 blk(256);

  // 2) fused QKV projection (N=6144, 3072 blocks); V written transposed
  gemm_qkv<<<dim3(3 * D / BN, M / BM), blk, 0, stream>>>(
      xb, wqkv, qb, kb, vtb, bq, bk, bv, D, D, S);

  // 3) scores = Q K^T * inv_std (fp32 out, causal block skip)
  const float inv_std = 1.f / sqrtf((float)D);
  gemm_nt<1, float><<<dim3(S / BN, S / BM, B), blk, 0, stream>>>(
      qb, kb, sc, nullptr, inv_std, S, S, D, (size_t)S * D, (size_t)S * D, (size_t)S * S);

  // 4) causal softmax -> bf16 attn
  softmax_causal<<<dim3(B * S), blk, 0, stream>>>(sc, pb, S);

  // 5) ctx = attn @ V  (via V^T, NT form; K-range capped at diagonal)
  gemm_nt<2, unsigned short><<<dim3(D / BN, S / BM, B), blk, 0, stream>>>(
      pb, vtb, cb, nullptr, 1.f, S, D, S, (size_t)S * S, (size_t)D * S, (size_t)S * D);

  // 6) out = ctx Wp^T + bp (fp32 out)
  gemm_nt<0, float><<<dim3(D / BN, M / BM), blk, 0, stream>>>(
      cb, wpb, out, bp, 1.f, M, D, D, 0, 0, 0);
}

// Round 4
// 671.153 us; speedup vs baseline: 1.3094x; 1.1425x over previous
//
#include <hip/hip_runtime.h>
#include <hip/hip_bf16.h>
#include <type_traits>
#include <math.h>

// ---------------------------------------------------------------------------
// Attention: out = softmax_causal((x Wq^T + bq)(x Wk^T + bk)^T / sqrt(D)) (x Wv^T + bv) Wp^T + bp
// B=4, S=2048, D=2048, fp32 in/out, bf16 MFMA compute.
//
// R3: BK 32 -> 64 (32 MFMA per barrier drain) + XOR-swizzled LDS layout.
// Physical 16B slot p of row r holds logical slot p ^ (r&7); staging picks
// the swizzled GLOBAL column per lane (free — lane-constant), fragment reads
// XOR their slot by (fr&7) (free — lane-constant). Kills the 4-way bank
// conflicts of the R2 layout; required for BK=64 (row stride 128B).
//
// Workspace layout (256 MB):
//   [0,32)MB    xb    bf16 x              [8192,2048]
//   [32,56)MB   wqkv  bf16 [Wq;Wk;Wv]     [6144,2048]
//   [56,64)MB   wpb   bf16 Wp             [2048,2048]
//   [64,96)MB   qb    bf16 Q              (later reused as attn P)
//   [96,128)MB  kb    bf16 K              (later reused as ctx)
//   [160,192)MB vtb   bf16 V^T per batch  [B][D][S]
//   [192,256)MB sc    fp32 scores         [B,S,S]
// ---------------------------------------------------------------------------

typedef __bf16 bf16x8_t __attribute__((ext_vector_type(8)));
typedef float f32x4_t __attribute__((ext_vector_type(4)));
typedef unsigned short u16x8_t __attribute__((ext_vector_type(8)));

#define BM 128
#define BN 128
#define BK 64

__device__ inline unsigned short f2bf(float f) {
  unsigned int u = __builtin_bit_cast(unsigned int, f);
  unsigned int r = u + 0x7fffu + ((u >> 16) & 1u);
  return (unsigned short)(r >> 16);
}

// async global->LDS, 16B per lane; lds dest = wave-uniform base + lane*16
__device__ inline void gl2lds16(const unsigned short* g, unsigned short* l) {
  __builtin_amdgcn_global_load_lds(
      (const __attribute__((address_space(1))) unsigned int*)g,
      (__attribute__((address_space(3))) unsigned int*)l, 16, 0, 0);
}

// ---------------- cast fp32 -> bf16 (x input) ------------------------------
__global__ __launch_bounds__(256) void cast_f32_bf16(
    const float* __restrict__ in, unsigned short* __restrict__ out, long n4) {
  long i = blockIdx.x * 256L + threadIdx.x;
  if (i >= n4) return;
  float4 f = ((const float4*)in)[i];
  ushort4 u;
  u.x = f2bf(f.x); u.y = f2bf(f.y); u.z = f2bf(f.z); u.w = f2bf(f.w);
  ((ushort4*)out)[i] = u;
}

// ---------------- fused 4-weight cast: blockIdx.y selects matrix -----------
__global__ __launch_bounds__(256) void cast_w4(
    const float* __restrict__ w0, const float* __restrict__ w1,
    const float* __restrict__ w2, const float* __restrict__ w3,
    unsigned short* __restrict__ o0, unsigned short* __restrict__ o1,
    unsigned short* __restrict__ o2, unsigned short* __restrict__ o3,
    long n4) {
  long i = blockIdx.x * 256L + threadIdx.x;
  if (i >= n4) return;
  const float* in; unsigned short* out;
  switch (blockIdx.y) {
    case 0: in = w0; out = o0; break;
    case 1: in = w1; out = o1; break;
    case 2: in = w2; out = o2; break;
    default: in = w3; out = o3; break;
  }
  float4 f = ((const float4*)in)[i];
  ushort4 u;
  u.x = f2bf(f.x); u.y = f2bf(f.y); u.z = f2bf(f.z); u.w = f2bf(f.w);
  ((ushort4*)out)[i] = u;
}

// ===================== shared GEMM K-loop (macro body) =====================
// Tile [128][64] bf16 = 16 KB = 16 chunks of 1 KB (8 rows x 8 slots of 16B).
// Wave w stages chunks 4w..4w+3 of both tiles. Lane l -> chunk-local row
// lr=l>>3, physical slot p=l&7; global column fetched = (p ^ lr)*8 elems
// (the swizzle). Fragment read of logical slot s at row r uses physical
// slot s ^ (r&7); r&7 == fr&7 (row offsets are multiples of 16).
#define GEMM_PROLOGUE()                                                        \
  const int tid = threadIdx.x;                                                 \
  const int lane = tid & 63;                                                   \
  const int wave = tid >> 6;                                                   \
  const int wm = (wave >> 1) * 64;                                             \
  const int wn = (wave & 1) * 64;                                              \
  __shared__ unsigned short smem[2 * BM * BK]; /* 32 KB */                     \
  unsigned short* As = smem;                                                   \
  unsigned short* Bs = smem + BM * BK;                                         \
  const int lr = lane >> 3;                                                    \
  const int swcol = ((lane & 7) ^ lr) * 8;                                     \
  const int cbase = wave * 4;                                                  \
  f32x4_t acc[4][4] = {};                                                      \
  const int fr = lane & 15;                                                    \
  const int q4 = lane >> 4;                                                    \
  const int fo0 = ((q4 ^ (fr & 7)) * 8);       /* kk=0 slot (swizzled) */      \
  const int fo1 = (((q4 + 4) ^ (fr & 7)) * 8); /* kk=1 slot (swizzled) */

#define GEMM_KLOOP(Ab, Bb, K, Keff)                                            \
  for (int k0 = 0; k0 < (Keff); k0 += BK) {                                    \
    __syncthreads();                                                           \
    _Pragma("unroll")                                                          \
    for (int i = 0; i < 4; i++) {                                              \
      const int c = cbase + i;                                                 \
      gl2lds16((Ab) + (size_t)(c * 8 + lr) * (K) + k0 + swcol, As + c * 512);  \
      gl2lds16((Bb) + (size_t)(c * 8 + lr) * (K) + k0 + swcol, Bs + c * 512);  \
    }                                                                          \
    __syncthreads();                                                           \
    {                                                                          \
      bf16x8_t af[4], bfv[4];                                                  \
      _Pragma("unroll")                                                        \
      for (int mi = 0; mi < 4; mi++)                                           \
        af[mi] = __builtin_bit_cast(                                           \
            bf16x8_t, *(const u16x8_t*)&As[(wm + mi * 16 + fr) * BK + fo0]);   \
      _Pragma("unroll")                                                        \
      for (int ni = 0; ni < 4; ni++)                                           \
        bfv[ni] = __builtin_bit_cast(                                          \
            bf16x8_t, *(const u16x8_t*)&Bs[(wn + ni * 16 + fr) * BK + fo0]);   \
      _Pragma("unroll")                                                        \
      for (int mi = 0; mi < 4; mi++)                                           \
        _Pragma("unroll")                                                      \
        for (int ni = 0; ni < 4; ni++)                                         \
          acc[mi][ni] = __builtin_amdgcn_mfma_f32_16x16x32_bf16(               \
              af[mi], bfv[ni], acc[mi][ni], 0, 0, 0);                          \
      _Pragma("unroll")                                                        \
      for (int mi = 0; mi < 4; mi++)                                           \
        af[mi] = __builtin_bit_cast(                                           \
            bf16x8_t, *(const u16x8_t*)&As[(wm + mi * 16 + fr) * BK + fo1]);   \
      _Pragma("unroll")                                                        \
      for (int ni = 0; ni < 4; ni++)                                           \
        bfv[ni] = __builtin_bit_cast(                                          \
            bf16x8_t, *(const u16x8_t*)&Bs[(wn + ni * 16 + fr) * BK + fo1]);   \
      _Pragma("unroll")                                                        \
      for (int mi = 0; mi < 4; mi++)                                           \
        _Pragma("unroll")                                                      \
        for (int ni = 0; ni < 4; ni++)                                         \
          acc[mi][ni] = __builtin_amdgcn_mfma_f32_16x16x32_bf16(               \
              af[mi], bfv[ni], acc[mi][ni], 0, 0, 0);                          \
    }                                                                          \
  }

// ---------------- generic NT GEMM (modes 0/1/2) ----------------------------
// MODE 0: plain. MODE 1: causal block skip. MODE 2: causal K-limit.
template <int MODE, typename OutT>
__global__ __launch_bounds__(256) void gemm_nt(
    const unsigned short* __restrict__ A, const unsigned short* __restrict__ B,
    OutT* __restrict__ C, const float* __restrict__ bias, float alpha,
    int M, int N, int K, size_t sA, size_t sB, size_t sC) {
  const int bm = blockIdx.y * BM;
  const int bn = blockIdx.x * BN;
  if (MODE == 1 && bn >= bm + BM) return;
  int Keff = K;
  if (MODE == 2) { int kl = bm + BM; Keff = kl < K ? kl : K; }

  A += (size_t)blockIdx.z * sA;
  B += (size_t)blockIdx.z * sB;
  C += (size_t)blockIdx.z * sC;

  GEMM_PROLOGUE();
  const unsigned short* Ab = A + (size_t)bm * K;
  const unsigned short* Bb = B + (size_t)bn * K;
  GEMM_KLOOP(Ab, Bb, K, Keff);

  const int cr = (lane >> 4) * 4;
  const int cc = lane & 15;
#pragma unroll
  for (int ni = 0; ni < 4; ni++) {
    const int col = bn + wn + ni * 16 + cc;
    const float bs = bias ? bias[col] : 0.f;
#pragma unroll
    for (int mi = 0; mi < 4; mi++) {
      const int row = bm + wm + mi * 16 + cr;
#pragma unroll
      for (int r = 0; r < 4; r++) {
        float v = acc[mi][ni][r] * alpha + bs;
        if constexpr (std::is_same_v<OutT, float>)
          C[(size_t)(row + r) * N + col] = v;
        else
          C[(size_t)(row + r) * N + col] = f2bf(v);
      }
    }
  }
}

// ---------------- fused QKV GEMM: N = 3*D, triple-destination epilogue -----
__global__ __launch_bounds__(256) void gemm_qkv(
    const unsigned short* __restrict__ A, const unsigned short* __restrict__ Bw,
    unsigned short* __restrict__ Q, unsigned short* __restrict__ Kd,
    unsigned short* __restrict__ Vt,
    const float* __restrict__ bq, const float* __restrict__ bk,
    const float* __restrict__ bv, int K, int D, int S) {
  const int bm = blockIdx.y * BM;
  const int bn = blockIdx.x * BN;

  GEMM_PROLOGUE();
  const unsigned short* Ab = A + (size_t)bm * K;
  const unsigned short* Bb = Bw + (size_t)bn * K;
  GEMM_KLOOP(Ab, Bb, K, K);

  const int cr = (lane >> 4) * 4;
  const int cc = lane & 15;
#pragma unroll
  for (int ni = 0; ni < 4; ni++) {
    const int col = bn + wn + ni * 16 + cc;       // [0, 3D)
    const int sel = col >> 11;                    // 0:Q 1:K 2:V (D=2048)
    const int idx = col & (D - 1);
    const float bs = (sel == 0 ? bq : sel == 1 ? bk : bv)[idx];
#pragma unroll
    for (int mi = 0; mi < 4; mi++) {
      const int row = bm + wm + mi * 16 + cr;
      if (sel < 2) {
        unsigned short* dst = sel == 0 ? Q : Kd;
#pragma unroll
        for (int r = 0; r < 4; r++)
          dst[(size_t)(row + r) * D + idx] = f2bf(acc[mi][ni][r] + bs);
      } else {
        const int b = row >> 11;                  // S=2048
        const int s = row & (S - 1);              // multiple of 4
        ushort4 pack;
        pack.x = f2bf(acc[mi][ni][0] + bs);
        pack.y = f2bf(acc[mi][ni][1] + bs);
        pack.z = f2bf(acc[mi][ni][2] + bs);
        pack.w = f2bf(acc[mi][ni][3] + bs);
        *(ushort4*)&Vt[(size_t)b * D * S + (size_t)idx * S + s] = pack;
      }
    }
  }
}

// ---------------- causal softmax: fp32 scores row -> bf16 attn row ----------
__global__ __launch_bounds__(256) void softmax_causal(
    const float* __restrict__ Sc, unsigned short* __restrict__ P, int n) {
  const int row = blockIdx.x;
  const int q = row & (n - 1);
  const float* srow = Sc + (size_t)row * n;
  unsigned short* prow = P + (size_t)row * n;
  const int tid = threadIdx.x, lane = tid & 63, wid = tid >> 6;
  __shared__ float red[4];

  float m = -3.0e38f;
  for (int j = tid; j <= q; j += 256) m = fmaxf(m, srow[j]);
#pragma unroll
  for (int o = 32; o; o >>= 1) m = fmaxf(m, __shfl_down(m, o, 64));
  if (lane == 0) red[wid] = m;
  __syncthreads();
  m = fmaxf(fmaxf(red[0], red[1]), fmaxf(red[2], red[3]));
  __syncthreads();

  float s = 0.f;
  for (int j = tid; j <= q; j += 256) s += __expf(srow[j] - m);
#pragma unroll
  for (int o = 32; o; o >>= 1) s += __shfl_down(s, o, 64);
  if (lane == 0) red[wid] = s;
  __syncthreads();
  s = red[0] + red[1] + red[2] + red[3];
  const float inv = 1.f / s;

  for (int j = tid; j < n; j += 256) {
    float v = (j <= q) ? __expf(srow[j] - m) * inv : 0.f;
    prow[j] = f2bf(v);
  }
}

// ---------------------------------------------------------------------------
extern "C" void kernel_launch(void* const* d_in, const int* in_sizes, int n_in,
                              void* d_out, int out_size, void* d_ws, size_t ws_size,
                              hipStream_t stream) {
  const int B = 4, S = 2048, D = 2048;
  const int M = B * S;  // 8192

  const float* x  = (const float*)d_in[0];
  // d_in[1] = mask: guaranteed causal tril, hardcoded in kernels
  const float* Wq = (const float*)d_in[2];
  const float* bq = (const float*)d_in[3];
  const float* Wk = (const float*)d_in[4];
  const float* bk = (const float*)d_in[5];
  const float* Wv = (const float*)d_in[6];
  const float* bv = (const float*)d_in[7];
  const float* Wp = (const float*)d_in[8];
  const float* bp = (const float*)d_in[9];
  float* out = (float*)d_out;

  char* ws = (char*)d_ws;
  const size_t MB = 1ull << 20;
  unsigned short* xb   = (unsigned short*)(ws + 0);
  unsigned short* wqkv = (unsigned short*)(ws + 32 * MB);  // [6144,2048]
  unsigned short* wpb  = (unsigned short*)(ws + 56 * MB);
  unsigned short* qb   = (unsigned short*)(ws + 64 * MB);
  unsigned short* kb   = (unsigned short*)(ws + 96 * MB);
  unsigned short* vtb  = (unsigned short*)(ws + 160 * MB);
  float*          sc   = (float*)(ws + 192 * MB);
  unsigned short* pb   = qb;  // attn reuses Q (dead after scores GEMM)
  unsigned short* cb   = kb;  // ctx reuses K (dead after scores GEMM)

  const long nx = (long)M * D;
  const long nw = (long)D * D;

  // 1) casts: x, then all 4 weights in one launch (into stacked layout)
  cast_f32_bf16<<<dim3((unsigned)((nx / 4 + 255) / 256)), 256, 0, stream>>>(x, xb, nx / 4);
  cast_w4<<<dim3((unsigned)((nw / 4 + 255) / 256), 4), 256, 0, stream>>>(
      Wq, Wk, Wv, Wp,
      wqkv, wqkv + (size_t)D * D, wqkv + 2 * (size_t)D * D, wpb, nw / 4);

  const dim3 blk(256);

  // 2) fused QKV projection (N=6144, 3072 blocks); V written transposed
  gemm_qkv<<<dim3(3 * D / BN, M / BM), blk, 0, stream>>>(
      xb, wqkv, qb, kb, vtb, bq, bk, bv, D, D, S);

  // 3) scores = Q K^T * inv_std (fp32 out, causal block skip)
  const float inv_std = 1.f / sqrtf((float)D);
  gemm_nt<1, float><<<dim3(S / BN, S / BM, B), blk, 0, stream>>>(
      qb, kb, sc, nullptr, inv_std, S, S, D, (size_t)S * D, (size_t)S * D, (size_t)S * S);

  // 4) causal softmax -> bf16 attn
  softmax_causal<<<dim3(B * S), blk, 0, stream>>>(sc, pb, S);

  // 5) ctx = attn @ V  (via V^T, NT form; K-range capped at diagonal)
  gemm_nt<2, unsigned short><<<dim3(D / BN, S / BM, B), blk, 0, stream>>>(
      pb, vtb, cb, nullptr, 1.f, S, D, S, (size_t)S * S, (size_t)D * S, (size_t)S * D);

  // 6) out = ctx Wp^T + bp (fp32 out)
  gemm_nt<0, float><<<dim3(D / BN, M / BM), blk, 0, stream>>>(
      cb, wpb, out, bp, 1.f, M, D, D, 0, 0, 0);
}